// Round 5
// baseline (1381.997 us; speedup 1.0000x reference)
//
#include <hip/hip_runtime.h>

// ODEFunc CNF dynamics, B=1e6 rows:
//   h1 = elu(W1 z + b1); [h2|u2|v2] = W2 [h1|u|v]; out01 = W3 elu(h2) + b3;
//   trace = W3[0,:]·(elu'(h2)*u2) + W3[1,:]·(elu'(h2)*v2); out[:,2] = -trace
//
// R5. History of the register war:
//   R1 cap(256,2): 128 arch + 128 AGPR split, accvgpr shuffle      -> 349us
//   R2 no bounds:  64-reg cap, 192 floats to scratch (768MB wr)    -> 5632us
//   R3 cap(256,1): 104 arch + ~150 AGPR split                      -> 441us
//   R4 cap(256,4): 64 arch + 64 AGPR split (occ 41% ~ half of 8w)  -> 638us
// Pattern: allocator targets high-occupancy arch budget, overflows into
// AGPRs, each touched accumulator FMA becomes read+fma+write (3x VALU).
// Fix: (a) amdgpu_waves_per_eu(4,4) pins budget at exactly 128 arch regs;
//      (b) W1-FOLDING: u[j]=g_j*W1[j,0] -> precompute W2u=W2*W1[:,0]^T,
//          W2v=W2*W1[:,1]^T (pre-kernel into d_ws); per-lane j-state
//          shrinks to {h,g}. elu(a)=relu(a)+exp(min(a,0))-1, elu'=exp(min(a,0))
//          (branch-free, no cndmask).
// State: acc/d0/d1[16]=48 + h/g[8]=16 + misc ~16 => ~80 regs < 128.
// Weights wave-uniform -> s_load (SMEM pipe), SGPR operand of v_fma (free).

template <bool FOLD>
__global__ __launch_bounds__(256) __attribute__((amdgpu_waves_per_eu(4, 4)))
void odefunc_kernel(const float* __restrict__ zin,
                    const float* __restrict__ W1, const float* __restrict__ b1,
                    const float* __restrict__ W2, const float* __restrict__ b2,
                    const float* __restrict__ W3, const float* __restrict__ b3,
                    const float* __restrict__ W2u, const float* __restrict__ W2v,
                    float* __restrict__ out, int B)
{
    int r = blockIdx.x * blockDim.x + threadIdx.x;
    if (r >= B) return;

    float z0 = zin[3 * r + 0];
    float z1 = zin[3 * r + 1];

    float out0 = b3[0], out1 = b3[1], tr = 0.f;

#pragma unroll 1   // kt stays rolled: live acc state is 48 regs, not 192
    for (int kt = 0; kt < 4; ++kt) {
        // Opaque z copies: block LICM/CSE from hoisting the per-tile
        // layer-1 recompute (which would resurrect 128+ live values).
        float z0w = z0, z1w = z1;
        asm volatile("" : "+v"(z0w), "+v"(z1w));

        float acc[16], d0[16], d1[16];
#pragma unroll
        for (int k = 0; k < 16; ++k) {
            acc[k] = b2[kt * 16 + k];   // uniform -> s_load
            d0[k] = 0.f;
            d1[k] = 0.f;
        }

#pragma unroll
        for (int jc = 0; jc < 8; ++jc) {
            // ---- layer 1 for j in [8*jc, 8*jc+8): branch-free elu ----
            float h[8], g[8], u[8], v[8];
#pragma unroll
            for (int jj = 0; jj < 8; ++jj) {
                int j = jc * 8 + jj;
                float w0 = W1[2 * j + 0];   // uniform -> s_load
                float w1 = W1[2 * j + 1];
                float a = fmaf(w0, z0w, fmaf(w1, z1w, b1[j]));
                float ex = __expf(fminf(a, 0.f));   // == elu'(a), branch-free
                h[jj] = fmaxf(a, 0.f) + (ex - 1.f); // elu(a)
                if (FOLD) {
                    g[jj] = ex;
                } else {
                    u[jj] = ex * w0;
                    v[jj] = ex * w1;
                }
            }
            // ---- partial layer 2: 16 k x 8 j x 3 matvecs ----
#pragma unroll
            for (int k = 0; k < 16; ++k) {
                int base = (kt * 16 + k) * 64 + jc * 8;
                const float* wr  = W2 + base;            // uniform
                const float* wru = FOLD ? (W2u + base) : nullptr;
                const float* wrv = FOLD ? (W2v + base) : nullptr;
#pragma unroll
                for (int jj = 0; jj < 8; ++jj) {
                    float w = wr[jj];                    // SGPR fma operand
                    acc[k] = fmaf(w, h[jj], acc[k]);
                    if (FOLD) {
                        d0[k] = fmaf(wru[jj], g[jj], d0[k]);
                        d1[k] = fmaf(wrv[jj], g[jj], d1[k]);
                    } else {
                        d0[k] = fmaf(w, u[jj], d0[k]);
                        d1[k] = fmaf(w, v[jj], d1[k]);
                    }
                }
            }
        }

        // ---- elu + layer-3 fold for this k-tile ----
#pragma unroll
        for (int k = 0; k < 16; ++k) {
            float a = acc[k];
            float ex = __expf(fminf(a, 0.f));
            float hh = fmaxf(a, 0.f) + (ex - 1.f);
            float w30 = W3[kt * 16 + k];            // W3[0,k]
            float w31 = W3[64 + kt * 16 + k];       // W3[1,k]
            out0 = fmaf(w30, hh, out0);
            out1 = fmaf(w31, hh, out1);
            tr = fmaf(w30, ex * d0[k], fmaf(w31, ex * d1[k], tr));
        }
    }

    out[3 * r + 0] = out0;
    out[3 * r + 1] = out1;
    out[3 * r + 2] = -tr;
}

// Pre-kernel: fold W1 columns into W2 -> W2u/W2v in workspace.
__global__ void fold_weights(const float* __restrict__ W2,
                             const float* __restrict__ W1,
                             float* __restrict__ ws)
{
    int i = blockIdx.x * blockDim.x + threadIdx.x;   // 0..4095
    if (i < 4096) {
        int j = i & 63;
        float w = W2[i];
        ws[i]        = w * W1[2 * j + 0];   // W2u[k,j]
        ws[4096 + i] = w * W1[2 * j + 1];   // W2v[k,j]
    }
}

extern "C" void kernel_launch(void* const* d_in, const int* in_sizes, int n_in,
                              void* d_out, int out_size, void* d_ws, size_t ws_size,
                              hipStream_t stream) {
    // d_in: 0=t(unused) 1=z_and_logp 2=W1 3=b1 4=W2 5=b2 6=W3 7=b3
    const float* zin = (const float*)d_in[1];
    const float* W1  = (const float*)d_in[2];
    const float* b1  = (const float*)d_in[3];
    const float* W2  = (const float*)d_in[4];
    const float* b2  = (const float*)d_in[5];
    const float* W3  = (const float*)d_in[6];
    const float* b3  = (const float*)d_in[7];
    float* out = (float*)d_out;
    float* wsf = (float*)d_ws;

    int B = in_sizes[1] / 3;
    int grid = (B + 255) / 256;

    if (ws_size >= 2 * 4096 * sizeof(float)) {
        fold_weights<<<16, 256, 0, stream>>>(W2, W1, wsf);
        odefunc_kernel<true><<<grid, 256, 0, stream>>>(
            zin, W1, b1, W2, b2, W3, b3, wsf, wsf + 4096, out, B);
    } else {
        odefunc_kernel<false><<<grid, 256, 0, stream>>>(
            zin, W1, b1, W2, b2, W3, b3, nullptr, nullptr, out, B);
    }
}

// Round 6
// 139.550 us; speedup vs baseline: 9.9032x; 9.9032x over previous
//
#include <hip/hip_runtime.h>
#include <hip/hip_bf16.h>

// ODEFunc CNF dynamics, B=1e6 rows, H=64:
//   h1 = elu(W1 z + b1); [h2|u2|v2] = [h1|u|v] W2^T; out01 = W3 elu(h2)+b3;
//   trace = W3[0,:]*(elu'(h2)*u2) + W3[1,:]*(elu'(h2)*v2); out[:,2] = -trace
//
// R6: MFMA rewrite. R1-R5 (scalar VALU, one thread/row) all lost the register
// war (allocator splits unified file, accvgpr/scratch traffic 2-16x): best 349us.
// Here: per wave, 16-row tiles. D = W2 * H^T via mfma_f32_16x16x32_bf16:
//   A-frag = W2 sub-block  (A[m=lane&15][k=quad*8+jj] - m120-verified layout)
//   B-frag = [h|u|v]^T     (B[k=quad*8+jj][n=lane&15]): lane computes layer-1
//            for row lane&15, j=jt*32+quad*8+jj -> frag built in-register.
//   D[k][row]: row = lane&15, k = mt*16 + quad*4 + reg  -> W3-fold reduction is
//   in-lane over 16 k + 2 shfl_xor stages (cross-quad). No LDS anywhere.
// Accumulators live in AGPRs (MFMA-native). Invariant weights ~128 VGPRs;
// amdgpu_waves_per_eu(2,2) pins the 256-reg unified budget (2 waves/SIMD).
// bf16 operands / fp32 accum: est absmax ~1e-2 < 1.77e-2 threshold.

typedef short bf16x8 __attribute__((ext_vector_type(8)));
typedef float f32x4  __attribute__((ext_vector_type(4)));

static __device__ __forceinline__ short f2bf(float x) {
    __hip_bfloat16 b = __float2bfloat16(x);
    return __builtin_bit_cast(short, b);
}

__global__ __launch_bounds__(256) __attribute__((amdgpu_waves_per_eu(2, 2)))
void odefunc_mfma(const float* __restrict__ zin,
                  const float* __restrict__ W1, const float* __restrict__ b1,
                  const float* __restrict__ W2, const float* __restrict__ b2,
                  const float* __restrict__ W3, const float* __restrict__ b3,
                  float* __restrict__ out, int B, int ntiles)
{
    const int lane = threadIdx.x & 63;
    const int quad = lane >> 4;      // 0..3
    const int col  = lane & 15;      // row-within-tile (B/D n-index)

    const int wid    = blockIdx.x * (blockDim.x >> 6) + (threadIdx.x >> 6);
    const int nwaves = gridDim.x * (blockDim.x >> 6);

    // ---- Loop-invariant: W2 as A-operand fragments (4 mtiles x 2 jtiles) ----
    bf16x8 aW2[4][2];
#pragma unroll
    for (int mt = 0; mt < 4; ++mt)
#pragma unroll
        for (int jt = 0; jt < 2; ++jt) {
            const float* p = W2 + (mt * 16 + col) * 64 + jt * 32 + quad * 8;
#pragma unroll
            for (int jj = 0; jj < 8; ++jj) aW2[mt][jt][jj] = f2bf(p[jj]);
        }

    // ---- Loop-invariant: layer-1 constants for this lane's 16 j's ----
    float w0v[2][8], w1v[2][8], b1v[2][8];
#pragma unroll
    for (int jt = 0; jt < 2; ++jt)
#pragma unroll
        for (int jj = 0; jj < 8; ++jj) {
            int j = jt * 32 + quad * 8 + jj;
            w0v[jt][jj] = W1[2 * j];
            w1v[jt][jj] = W1[2 * j + 1];
            b1v[jt][jj] = b1[j];
        }

    // ---- Loop-invariant: epilogue constants for this lane's 16 k's ----
    float b2v[4][4], w30v[4][4], w31v[4][4];
#pragma unroll
    for (int mt = 0; mt < 4; ++mt)
#pragma unroll
        for (int i = 0; i < 4; ++i) {
            int k = mt * 16 + quad * 4 + i;
            b2v[mt][i]  = b2[k];
            w30v[mt][i] = W3[k];        // W3[0,k]
            w31v[mt][i] = W3[64 + k];   // W3[1,k]
        }
    const float b30 = b3[0], b31 = b3[1];
    const f32x4 zero4 = {0.f, 0.f, 0.f, 0.f};

    for (int t = wid; t < ntiles; t += nwaves) {
        int row = t * 16 + col;
        int rl = row < B ? row : B - 1;
        float z0 = zin[3 * rl + 0];
        float z1 = zin[3 * rl + 1];

        // ---- layer 1 (branch-free elu) + B-fragments for [h|u|v] ----
        bf16x8 Ah[2], Au[2], Av[2];
#pragma unroll
        for (int jt = 0; jt < 2; ++jt)
#pragma unroll
            for (int jj = 0; jj < 8; ++jj) {
                float w0 = w0v[jt][jj], w1 = w1v[jt][jj];
                float a  = fmaf(w0, z0, fmaf(w1, z1, b1v[jt][jj]));
                float ex = __expf(fminf(a, 0.f));       // elu'(a)
                float h  = fmaxf(a, 0.f) + (ex - 1.f);  // elu(a)
                Ah[jt][jj] = f2bf(h);
                Au[jt][jj] = f2bf(ex * w0);
                Av[jt][jj] = f2bf(ex * w1);
            }

        // ---- MFMA: D = W2 * [h|u|v]^T, K=64 as 2 chained k-steps ----
        f32x4 accH[4], accU[4], accV[4];
#pragma unroll
        for (int mt = 0; mt < 4; ++mt) {
            accH[mt] = __builtin_amdgcn_mfma_f32_16x16x32_bf16(aW2[mt][0], Ah[0], zero4, 0, 0, 0);
            accH[mt] = __builtin_amdgcn_mfma_f32_16x16x32_bf16(aW2[mt][1], Ah[1], accH[mt], 0, 0, 0);
            accU[mt] = __builtin_amdgcn_mfma_f32_16x16x32_bf16(aW2[mt][0], Au[0], zero4, 0, 0, 0);
            accU[mt] = __builtin_amdgcn_mfma_f32_16x16x32_bf16(aW2[mt][1], Au[1], accU[mt], 0, 0, 0);
            accV[mt] = __builtin_amdgcn_mfma_f32_16x16x32_bf16(aW2[mt][0], Av[0], zero4, 0, 0, 0);
            accV[mt] = __builtin_amdgcn_mfma_f32_16x16x32_bf16(aW2[mt][1], Av[1], accV[mt], 0, 0, 0);
        }

        // ---- epilogue: elu + W3 fold, in-lane over this lane's 16 k's ----
        float o0 = 0.f, o1 = 0.f, trc = 0.f;
#pragma unroll
        for (int mt = 0; mt < 4; ++mt)
#pragma unroll
            for (int i = 0; i < 4; ++i) {
                float a2  = accH[mt][i] + b2v[mt][i];
                float ex2 = __expf(fminf(a2, 0.f));
                float hh  = fmaxf(a2, 0.f) + (ex2 - 1.f);
                o0  = fmaf(w30v[mt][i], hh, o0);
                o1  = fmaf(w31v[mt][i], hh, o1);
                trc = fmaf(ex2, fmaf(w30v[mt][i], accU[mt][i],
                                     w31v[mt][i] * accV[mt][i]), trc);
            }

        // ---- cross-quad reduction (k spans quads): 2 butterfly stages ----
        o0  += __shfl_xor(o0, 16);  o0  += __shfl_xor(o0, 32);
        o1  += __shfl_xor(o1, 16);  o1  += __shfl_xor(o1, 32);
        trc += __shfl_xor(trc, 16); trc += __shfl_xor(trc, 32);

        if (lane < 16 && row < B) {
            out[3 * row + 0] = o0 + b30;
            out[3 * row + 1] = o1 + b31;
            out[3 * row + 2] = -trc;
        }
    }
}

extern "C" void kernel_launch(void* const* d_in, const int* in_sizes, int n_in,
                              void* d_out, int out_size, void* d_ws, size_t ws_size,
                              hipStream_t stream) {
    // d_in: 0=t(unused) 1=z_and_logp 2=W1 3=b1 4=W2 5=b2 6=W3 7=b3
    const float* zin = (const float*)d_in[1];
    const float* W1  = (const float*)d_in[2];
    const float* b1  = (const float*)d_in[3];
    const float* W2  = (const float*)d_in[4];
    const float* b2  = (const float*)d_in[5];
    const float* W3  = (const float*)d_in[6];
    const float* b3  = (const float*)d_in[7];
    float* out = (float*)d_out;

    int B = in_sizes[1] / 3;
    int ntiles = (B + 15) / 16;
    int grid = 1024;   // 4096 waves, grid-stride over 62500 tiles
    odefunc_mfma<<<grid, 256, 0, stream>>>(zin, W1, b1, W2, b2, W3, b3,
                                           out, B, ntiles);
}